// Round 2
// baseline (413.237 us; speedup 1.0000x reference)
//
#include <hip/hip_runtime.h>

#define SLEN  512
#define BATCH 256
#define NTAGS 128
#define NTHR  512   // 8 waves: j = tid&127, h = tid>>7 (i-range split 4-ways)

__global__ __launch_bounds__(NTHR) void viterbi_kernel(
    const float* __restrict__ em,      // [S,B,T]
    const int*   __restrict__ mask,    // [S,B]
    const float* __restrict__ start_t, // [T]
    const float* __restrict__ end_t,   // [T]
    const float* __restrict__ trans,   // [T,T]
    float* __restrict__ out)           // [B*S] tags (as float), then [B] scores (float)
{
    const int b   = blockIdx.x;
    const int tid = threadIdx.x;
    const int j   = tid & (NTAGS - 1);
    const int h   = tid >> 7;          // 0..3

    __shared__ float sc[NTAGS];
    __shared__ float pmax[4][NTAGS];
    __shared__ int   pidx[4][NTAGS];
    __shared__ int   maskv[SLEN];
    __shared__ unsigned char hist[SLEN - 1][NTAGS];   // 65408 B
    __shared__ unsigned char tagseq[SLEN];
    __shared__ float bestval_s;
    __shared__ int   bestj_s;

    // Preload this thread's transitions column chunk into registers:
    // trcol[k] = trans[(h*32+k)*128 + j]  (coalesced across j within a wave)
    float trcol[32];
#pragma unroll
    for (int k = 0; k < 32; ++k)
        trcol[k] = trans[(h * 32 + k) * NTAGS + j];

    // Mask column for this batch
    for (int t = tid; t < SLEN; t += NTHR)
        maskv[t] = mask[t * BATCH + b];

    // score0 = start + emissions[0]   (exact ref associativity)
    if (tid < NTAGS)
        sc[j] = start_t[j] + em[(size_t)b * NTAGS + j];
    __syncthreads();

    // Prefetch emissions row for t=1
    float em_next = em[(size_t)(1 * BATCH + b) * NTAGS + j];

    for (int t = 1; t < SLEN; ++t) {
        const float em_cur = em_next;
        if (t + 1 < SLEN)
            em_next = em[(size_t)((t + 1) * BATCH + b) * NTAGS + j];

        // Partial (max, argmax) over i in [h*32, h*32+32).
        // cand = fl(fl(sc[i] + trans[i][j]) + em[t][b][j])  — matches ref exactly.
        // Strict > with ascending i keeps the FIRST max (np.argmax tie rule).
        float best = -__builtin_inff();
        int   bidx = 0;
        const int base = h * 32;
#pragma unroll
        for (int k = 0; k < 32; ++k) {
            float c = (sc[base + k] + trcol[k]) + em_cur;
            if (c > best) { best = c; bidx = base + k; }
        }
        pmax[h][j] = best;
        pidx[h][j] = bidx;
        __syncthreads();

        if (h == 0) {
            // Combine 4 partials in ascending-h order, strict > keeps first-max.
            float bv = pmax[0][j]; int bi = pidx[0][j];
#pragma unroll
            for (int hh = 1; hh < 4; ++hh) {
                float v = pmax[hh][j];
                if (v > bv) { bv = v; bi = pidx[hh][j]; }
            }
            hist[t - 1][j] = (unsigned char)bi;   // recorded unconditionally (ref does too)
            if (maskv[t]) sc[j] = bv;             // where(mask, next, old)
        }
        __syncthreads();
    }

    // final = sc + end_transitions (reuse sc); first-occurrence argmax over 128 tags
    if (tid < NTAGS) sc[j] = sc[j] + end_t[j];
    __syncthreads();

    if (tid < 64) {
        float v  = sc[tid]; int bj = tid;
        float v1 = sc[tid + 64];
        if (v1 > v) { v = v1; bj = tid + 64; }   // tie keeps lower index
#pragma unroll
        for (int off = 32; off > 0; off >>= 1) {
            float ov = __shfl_xor(v, off, 64);
            int   oj = __shfl_xor(bj, off, 64);
            if (ov > v || (ov == v && oj < bj)) { v = ov; bj = oj; }
        }
        if (tid == 0) { bestval_s = v; bestj_s = bj; }
    }
    __syncthreads();

    // Backtrace: serial LDS chase by thread 0 into tagseq
    if (tid == 0) {
        int tag = bestj_s;
        tagseq[SLEN - 1] = (unsigned char)tag;
        for (int t = SLEN - 2; t >= 0; --t) {
            int prev = hist[t][tag];
            if (maskv[t + 1]) tag = prev;     // follow history only inside sequence
            tagseq[t] = (unsigned char)tag;
        }
        // best_path_score as float (harness reads d_out as float32)
        out[BATCH * SLEN + b] = bestval_s;
    }
    __syncthreads();

    // Coalesced tag writeout as float: out0 is tags.T -> [B, S] row-major
    out[b * SLEN + tid] = (float)tagseq[tid];
}

extern "C" void kernel_launch(void* const* d_in, const int* in_sizes, int n_in,
                              void* d_out, int out_size, void* d_ws, size_t ws_size,
                              hipStream_t stream) {
    const float* em      = (const float*)d_in[0];
    const int*   mask    = (const int*)d_in[1];
    const float* start_t = (const float*)d_in[2];
    const float* end_t   = (const float*)d_in[3];
    const float* trans   = (const float*)d_in[4];
    float* out = (float*)d_out;

    viterbi_kernel<<<dim3(BATCH), dim3(NTHR), 0, stream>>>(
        em, mask, start_t, end_t, trans, out);
}